// Round 6
// baseline (1203.619 us; speedup 1.0000x reference)
//
#include <hip/hip_runtime.h>

// DictLearn: W column-normalize -> power method (100 it) -> IHT sparse coding
// (50 it, K=64 hard threshold) -> X = W @ Gamma.
// Outputs in d_out: X [512*1024] fp32, Gamma [1024*1024] fp32, norms [50] fp32.
//
// R6 changes vs R5 (trajectory bit-identical: per-column k-ascending fmaf
// chains, select integer math, reduce trees, and eta all unchanged):
//  * k_iht_all: ONE 64-thread WAVE per batch row (was 256 threads). All
//    barriers become single-wave (trivial); radix select + compaction are
//    wave-synchronous shuffles; thread owns 16 columns (c = j*256+4t+e).
//    4 independent waves/CU desync -> L2 gather port stays fed during
//    other waves' select phases.
//  * Gather: 4k x 4group unroll = 16 saddr dwordx4 loads in flight.

#define DEV __device__ __forceinline__

constexpr int Nd = 512;    // signal dim
constexpr int Md = 1024;   // atoms
constexpr int Bd = 1024;   // batch
constexpr int Ksp = 64;    // sparsity K
constexpr int IHT = 50;

DEV float wave_reduce_f(float v) {
#pragma unroll
  for (int off = 32; off > 0; off >>= 1) v += __shfl_down(v, off);
  return v;
}
DEV double wave_reduce_d(double v) {
#pragma unroll
  for (int off = 32; off > 0; off >>= 1) v += __shfl_down(v, off);
  return v;
}
DEV float rfl_f(float v) {
  return __uint_as_float(__builtin_amdgcn_readfirstlane(__float_as_uint(v)));
}

__global__ void k_zero(double* dacc) {
  int t = threadIdx.x;
  if (t < 51) dacc[t] = 0.0;  // [0]=Yn2, [1..50]=norm accumulators
}

__global__ __launch_bounds__(256) void k_colnorm(const float* __restrict__ W,
                                                 float* __restrict__ cnorm) {
  int col = blockIdx.x * 256 + threadIdx.x;  // 1024 cols
  double ss = 0.0;
  for (int i = 0; i < Nd; ++i) {
    float w = W[(size_t)i * Md + col];
    ss = fma((double)w, (double)w, ss);
  }
  cnorm[col] = (float)sqrt(ss);
}

__global__ __launch_bounds__(256) void k_normalize(const float* __restrict__ W,
                                                   const float* __restrict__ cnorm,
                                                   float* __restrict__ Wn) {
  int idx = blockIdx.x * 256 + threadIdx.x;  // 512*1024
  Wn[idx] = W[idx] / cnorm[idx & (Md - 1)];
}

__global__ __launch_bounds__(256) void k_yn2(const float* __restrict__ Y,
                                             double* __restrict__ dacc) {
  double s = 0.0;
  for (int i = blockIdx.x * 256 + threadIdx.x; i < Bd * Nd; i += gridDim.x * 256) {
    float y = Y[i];
    s = fma((double)y, (double)y, s);
  }
  s = wave_reduce_d(s);
  __shared__ double red[4];
  int lane = threadIdx.x & 63, wid = threadIdx.x >> 6;
  if (lane == 0) red[wid] = s;
  __syncthreads();
  if (threadIdx.x == 0) atomicAdd(&dacc[0], red[0] + red[1] + red[2] + red[3]);
}

// C[m,n] = scale * sum_k A(m,k)*B(k,n); ta/tb: operand stored transposed.
// BMxBN tile, 256 threads, 4xTN per thread, BK=32, register double-buffered
// staging. Per-element accumulation k0-ascending, kk-ascending (bit-stable).
template <int BM, int BN, int TN>
__global__ __launch_bounds__(256) void k_gemm_t(const float* __restrict__ A, int lda, int ta,
                                                const float* __restrict__ B, int ldb, int tb,
                                                float* __restrict__ C, int ldc, int Kd,
                                                float scale) {
  constexpr int AE = 32 * BM / 256;
  constexpr int BE = 32 * BN / 256;
  __shared__ __align__(16) float As[32][BM + 4];  // [kk][m]
  __shared__ __align__(16) float Bs[32][BN + 4];  // [kk][n]
  const int tid = threadIdx.x;
  const int tx = tid % (BN / TN), ty = tid / (BN / TN);
  const int m0 = blockIdx.y * BM, n0 = blockIdx.x * BN;
  float ra[AE], rb[BE];
  float acc[4][TN];
#pragma unroll
  for (int i = 0; i < 4; ++i)
#pragma unroll
    for (int j = 0; j < TN; ++j) acc[i][j] = 0.f;

  auto loadA = [&](int k0) {
    if (!ta) {
      const int c = tid & 31, r0 = tid >> 5;
#pragma unroll
      for (int i = 0; i < AE; ++i)
        ra[i] = A[(size_t)(m0 + r0 + i * 8) * lda + (k0 + c)];
    } else {
      const int r = tid % BM, c0 = tid / BM;
#pragma unroll
      for (int i = 0; i < AE; ++i)
        ra[i] = A[(size_t)(k0 + c0 + i * (256 / BM)) * lda + (m0 + r)];
    }
  };
  auto storeA = [&]() {
    if (!ta) {
      const int c = tid & 31, r0 = tid >> 5;
#pragma unroll
      for (int i = 0; i < AE; ++i) As[c][r0 + i * 8] = ra[i];
    } else {
      const int r = tid % BM, c0 = tid / BM;
#pragma unroll
      for (int i = 0; i < AE; ++i) As[c0 + i * (256 / BM)][r] = ra[i];
    }
  };
  auto loadB = [&](int k0) {
    if (!tb) {
      const int c = tid % BN, r0 = tid / BN;
#pragma unroll
      for (int i = 0; i < BE; ++i)
        rb[i] = B[(size_t)(k0 + r0 + i * (256 / BN)) * ldb + (n0 + c)];
    } else {
      const int r = tid & 31, c0 = tid >> 5;
#pragma unroll
      for (int i = 0; i < BE; ++i)
        rb[i] = B[(size_t)(n0 + c0 + i * 8) * ldb + (k0 + r)];
    }
  };
  auto storeB = [&]() {
    if (!tb) {
      const int c = tid % BN, r0 = tid / BN;
#pragma unroll
      for (int i = 0; i < BE; ++i) Bs[r0 + i * (256 / BN)][c] = rb[i];
    } else {
      const int r = tid & 31, c0 = tid >> 5;
#pragma unroll
      for (int i = 0; i < BE; ++i) Bs[r][c0 + i * 8] = rb[i];
    }
  };

  loadA(0);
  loadB(0);
  storeA();
  storeB();
  __syncthreads();
  for (int k0 = 0; k0 < Kd; k0 += 32) {
    const bool more = (k0 + 32) < Kd;
    if (more) { loadA(k0 + 32); loadB(k0 + 32); }  // prefetch into regs
#pragma unroll
    for (int kk = 0; kk < 32; ++kk) {
      const float4 a4 = *(const float4*)&As[kk][ty * 4];
      const float aa[4] = {a4.x, a4.y, a4.z, a4.w};
      float bb[TN];
      if constexpr (TN == 4) {
        const float4 b4 = *(const float4*)&Bs[kk][tx * 4];
        bb[0] = b4.x; bb[1] = b4.y; bb[2] = b4.z; bb[3] = b4.w;
      } else {
        const float2 b2 = *(const float2*)&Bs[kk][tx * 2];
        bb[0] = b2.x; bb[1] = b2.y;
      }
#pragma unroll
      for (int i = 0; i < 4; ++i)
#pragma unroll
        for (int j = 0; j < TN; ++j) acc[i][j] = fmaf(aa[i], bb[j], acc[i][j]);
    }
    if (more) {
      __syncthreads();
      storeA();
      storeB();
      __syncthreads();
    }
  }
#pragma unroll
  for (int i = 0; i < 4; ++i) {
    if constexpr (TN == 4) {
      float4 o;
      o.x = acc[i][0] * scale; o.y = acc[i][1] * scale;
      o.z = acc[i][2] * scale; o.w = acc[i][3] * scale;
      *(float4*)&C[(size_t)(m0 + ty * 4 + i) * ldc + n0 + tx * 4] = o;
    } else {
      float2 o;
      o.x = acc[i][0] * scale; o.y = acc[i][1] * scale;
      *(float2*)&C[(size_t)(m0 + ty * 4 + i) * ldc + n0 + tx * 2] = o;
    }
  }
}

// XLA ErfInvF32 (Giles) — matches jax/XLA erf_inv on f32.
DEV float erfinv_xla(float x) {
  float w = -log1pf(-x * x);
  float p;
  if (w < 5.0f) {
    w = w - 2.5f;
    p = 2.81022636e-08f;
    p = fmaf(p, w, 3.43273939e-07f);
    p = fmaf(p, w, -3.5233877e-06f);
    p = fmaf(p, w, -4.39150654e-06f);
    p = fmaf(p, w, 0.00021858087f);
    p = fmaf(p, w, -0.00125372503f);
    p = fmaf(p, w, -0.00417768164f);
    p = fmaf(p, w, 0.246640727f);
    p = fmaf(p, w, 1.50140941f);
  } else {
    w = sqrtf(w) - 3.0f;
    p = -0.000200214257f;
    p = fmaf(p, w, 0.000100950558f);
    p = fmaf(p, w, 0.00134934322f);
    p = fmaf(p, w, -0.00367342844f);
    p = fmaf(p, w, 0.00573950773f);
    p = fmaf(p, w, -0.0076224613f);
    p = fmaf(p, w, 0.00943887047f);
    p = fmaf(p, w, 1.00167406f);
    p = fmaf(p, w, 2.83297682f);
  }
  return p * x;
}

#define TF_ROUND(r)                                  \
  {                                                  \
    x0 += x1;                                        \
    x1 = (x1 << (r)) | (x1 >> (32 - (r)));           \
    x1 ^= x0;                                        \
  }

// X0 = jax.random.normal(jax.random.key(42), (1,1024), f32), bit-exact bits.
__global__ void k_x0(float* __restrict__ X0) {
  unsigned i = threadIdx.x;  // 0..511; counter pair (i, i+512)
  unsigned x0 = i, x1 = i + 512u;
  const unsigned ks0 = 0u, ks1 = 42u, ks2 = 0x1BD11BDAu ^ 42u;
  x0 += ks0; x1 += ks1;
  TF_ROUND(13) TF_ROUND(15) TF_ROUND(26) TF_ROUND(6)  x0 += ks1; x1 += ks2 + 1u;
  TF_ROUND(17) TF_ROUND(29) TF_ROUND(16) TF_ROUND(24) x0 += ks2; x1 += ks0 + 2u;
  TF_ROUND(13) TF_ROUND(15) TF_ROUND(26) TF_ROUND(6)  x0 += ks0; x1 += ks1 + 3u;
  TF_ROUND(17) TF_ROUND(29) TF_ROUND(16) TF_ROUND(24) x0 += ks1; x1 += ks2 + 4u;
  TF_ROUND(13) TF_ROUND(15) TF_ROUND(26) TF_ROUND(6)  x0 += ks2; x1 += ks0 + 5u;
  const float lo = -0.99999994f;      // nextafter(-1, 0) in f32
  const float sqrt2 = 1.41421356237f; // rounds to 0x3FB504F3
  {
    float f = __uint_as_float((x0 >> 9) | 0x3f800000u) - 1.0f;
    float u = fmaxf(lo, f * 2.0f + lo);  // (hi-lo) == 2.0f exactly in f32
    X0[i] = sqrt2 * erfinv_xla(u);
  }
  {
    float f = __uint_as_float((x1 >> 9) | 0x3f800000u) - 1.0f;
    float u = fmaxf(lo, f * 2.0f + lo);
    X0[i + 512] = sqrt2 * erfinv_xla(u);
  }
}

// z0 = X0 @ Wn^T  (512 outputs, dot length 1024). One wave per row.
__global__ __launch_bounds__(256) void k_z0(const float* __restrict__ X0,
                                            const float* __restrict__ Wn,
                                            float* __restrict__ vout) {
  const int lane = threadIdx.x & 63, wid = threadIdx.x >> 6;
  const int row = blockIdx.x * 4 + wid;  // < 512
  const float4* wr = (const float4*)(Wn + (size_t)row * Md);
  const float4* x4 = (const float4*)X0;
  float s = 0.f;
#pragma unroll
  for (int e = 0; e < 4; ++e) {
    const float4 w4 = wr[lane + e * 64];
    const float4 xx = x4[lane + e * 64];
    s = fmaf(w4.x, xx.x, s); s = fmaf(w4.y, xx.y, s);
    s = fmaf(w4.z, xx.z, s); s = fmaf(w4.w, xx.w, s);
  }
  s = wave_reduce_f(s);
  if (lane == 0) vout[row] = s;
}

// vout = (vin @ Msym) * scale ; Msym is 512x512 symmetric. One wave per row.
__global__ __launch_bounds__(256) void k_pmv(const float* __restrict__ Mmat,
                                             const float* __restrict__ vin,
                                             float* __restrict__ vout, float scale) {
  const int lane = threadIdx.x & 63, wid = threadIdx.x >> 6;
  const int row = blockIdx.x * 4 + wid;  // < 512
  const float4* mr = (const float4*)(Mmat + (size_t)row * Nd);
  const float4* v4 = (const float4*)vin;
  float s = 0.f;
#pragma unroll
  for (int e = 0; e < 2; ++e) {
    const float4 m4 = mr[lane + e * 64];
    const float4 xx = v4[lane + e * 64];
    s = fmaf(m4.x, xx.x, s); s = fmaf(m4.y, xx.y, s);
    s = fmaf(m4.z, xx.z, s); s = fmaf(m4.w, xx.w, s);
  }
  s = wave_reduce_f(s);
  if (lane == 0) vout[row] = s * scale;
}

__global__ __launch_bounds__(512) void k_pfinal(const float* __restrict__ v99,
                                                const float* __restrict__ v100,
                                                float* __restrict__ cbuf) {
  __shared__ double r99[8], r100[8];
  const int t = threadIdx.x, lane = t & 63, wid = t >> 6;
  double a = (double)v99[t]; a *= a;
  double b = (double)v100[t]; b *= b;
  a = wave_reduce_d(a);
  b = wave_reduce_d(b);
  if (lane == 0) { r99[wid] = a; r100[wid] = b; }
  __syncthreads();
  if (t == 0) {
    double n99 = 0.0, n100 = 0.0;
    for (int i = 0; i < 8; ++i) { n99 += r99[i]; n100 += r100[i]; }
    float c = (float)(8.0 * sqrt(n100 / n99));  // last pre-norm ||X2||
    cbuf[0] = c;
    cbuf[1] = 1.0f / c;  // eta
  }
}

// ALL IHT iterations fused, ONE 64-thread WAVE per batch row (it=-1..49).
// Thread t owns columns c = j*256 + 4t + e (j,e in [0,4)): per-column fmaf
// chains, radix-select integer math, and reduce trees are bit-identical to
// R5 (which columns map to which thread doesn't affect bits).
__global__ __launch_bounds__(64) void k_iht_all(
    const float* __restrict__ Q, const float* __restrict__ YW,
    const float* __restrict__ cbuf, float* __restrict__ gdense,
    double* __restrict__ normacc) {
  __shared__ float u[Md];
  __shared__ float yws[Md];
  __shared__ float sval[Ksp];
  __shared__ int sidx[Ksp];
  __shared__ unsigned histbuf[2][256];  // [parity][bin]
  __shared__ unsigned sel_need, sel_prefix;
  __shared__ int scnt;

  const int t = threadIdx.x;  // 0..63 (one wave)
  const int b = blockIdx.x;
  const float eta = cbuf[1];
  const float4* YW4 = (const float4*)(YW + (size_t)b * Md);
  float4 yw[4], p[4];
#pragma unroll
  for (int j = 0; j < 4; ++j) {
    yw[j] = YW4[j * 64 + t];
    ((float4*)yws)[j * 64 + t] = yw[j];
  }
  histbuf[0][t] = 0u; histbuf[0][t + 64] = 0u; histbuf[0][t + 128] = 0u; histbuf[0][t + 192] = 0u;
  histbuf[1][t] = 0u; histbuf[1][t + 64] = 0u; histbuf[1][t + 128] = 0u; histbuf[1][t + 192] = 0u;
  const float* Qt = Q + t * 4;  // per-lane column base; row base is scalar

  for (int it = -1; it < IHT; ++it) {
    float vals[16];
    unsigned key[16];
    if (it >= 0) {
      const int cnt = scnt;
#pragma unroll
      for (int j = 0; j < 4; ++j) p[j] = make_float4(0.f, 0.f, 0.f, 0.f);
      int k = 0;
      for (; k + 4 <= cnt; k += 4) {  // 16 saddr loads in flight; k-ascending fma
        const int i0 = __builtin_amdgcn_readfirstlane(sidx[k]);
        const int i1 = __builtin_amdgcn_readfirstlane(sidx[k + 1]);
        const int i2 = __builtin_amdgcn_readfirstlane(sidx[k + 2]);
        const int i3 = __builtin_amdgcn_readfirstlane(sidx[k + 3]);
        const float g0 = rfl_f(sval[k]), g1 = rfl_f(sval[k + 1]);
        const float g2 = rfl_f(sval[k + 2]), g3 = rfl_f(sval[k + 3]);
        float4 q0[4], q1[4], q2[4], q3[4];
#pragma unroll
        for (int j = 0; j < 4; ++j) {
          q0[j] = *(const float4*)(Qt + (size_t)i0 * Md + j * 256);
          q1[j] = *(const float4*)(Qt + (size_t)i1 * Md + j * 256);
          q2[j] = *(const float4*)(Qt + (size_t)i2 * Md + j * 256);
          q3[j] = *(const float4*)(Qt + (size_t)i3 * Md + j * 256);
        }
#pragma unroll
        for (int j = 0; j < 4; ++j) {
          p[j].x = fmaf(g0, q0[j].x, p[j].x); p[j].x = fmaf(g1, q1[j].x, p[j].x);
          p[j].x = fmaf(g2, q2[j].x, p[j].x); p[j].x = fmaf(g3, q3[j].x, p[j].x);
          p[j].y = fmaf(g0, q0[j].y, p[j].y); p[j].y = fmaf(g1, q1[j].y, p[j].y);
          p[j].y = fmaf(g2, q2[j].y, p[j].y); p[j].y = fmaf(g3, q3[j].y, p[j].y);
          p[j].z = fmaf(g0, q0[j].z, p[j].z); p[j].z = fmaf(g1, q1[j].z, p[j].z);
          p[j].z = fmaf(g2, q2[j].z, p[j].z); p[j].z = fmaf(g3, q3[j].z, p[j].z);
          p[j].w = fmaf(g0, q0[j].w, p[j].w); p[j].w = fmaf(g1, q1[j].w, p[j].w);
          p[j].w = fmaf(g2, q2[j].w, p[j].w); p[j].w = fmaf(g3, q3[j].w, p[j].w);
        }
      }
      for (; k < cnt; ++k) {
        const int id = __builtin_amdgcn_readfirstlane(sidx[k]);
        const float g = rfl_f(sval[k]);
#pragma unroll
        for (int j = 0; j < 4; ++j) {
          const float4 q = *(const float4*)(Qt + (size_t)id * Md + j * 256);
          p[j].x = fmaf(g, q.x, p[j].x); p[j].y = fmaf(g, q.y, p[j].y);
          p[j].z = fmaf(g, q.z, p[j].z); p[j].w = fmaf(g, q.w, p[j].w);
        }
      }
#pragma unroll
      for (int j = 0; j < 4; ++j) ((float4*)u)[j * 64 + t] = p[j];  // u = P
      __syncthreads();
      if (it >= 1) {
        double part = 0.0;
        if (t < cnt) {
          const int id = sidx[t];
          part = (double)sval[t] * ((double)u[id] - 2.0 * (double)yws[id]);
        }
        part = wave_reduce_d(part);
        if (t == 0) atomicAdd(&normacc[it - 1], part);
      }
      __syncthreads();  // all u(P) reads done
#pragma unroll
      for (int j = 0; j < 4; ++j) {
        float4 uu;
        uu.x = -(eta * (p[j].x - yw[j].x)); uu.y = -(eta * (p[j].y - yw[j].y));
        uu.z = -(eta * (p[j].z - yw[j].z)); uu.w = -(eta * (p[j].w - yw[j].w));
        ((float4*)u)[j * 64 + t] = uu;
      }
      __syncthreads();
      if (t < cnt) u[sidx[t]] += sval[t];  // distinct indices, no race
      __syncthreads();
#pragma unroll
      for (int j = 0; j < 4; ++j) {
        const float4 mv = ((const float4*)u)[j * 64 + t];
        vals[j * 4 + 0] = mv.x; vals[j * 4 + 1] = mv.y;
        vals[j * 4 + 2] = mv.z; vals[j * 4 + 3] = mv.w;
      }
    } else {
#pragma unroll
      for (int j = 0; j < 4; ++j) {
        vals[j * 4 + 0] = eta * yw[j].x; vals[j * 4 + 1] = eta * yw[j].y;
        vals[j * 4 + 2] = eta * yw[j].z; vals[j * 4 + 3] = eta * yw[j].w;
      }
    }
#pragma unroll
    for (int e = 0; e < 16; ++e) key[e] = __float_as_uint(vals[e]) & 0x7fffffffu;

    // ---- radix select: exact bit pattern of the (K+1)-th largest |u| ----
    // wave-synchronous: LDS histogram (parity double-buffered; off-buffer
    // re-zeroed in the shadow), 4-chunk suffix scan in shuffles.
    unsigned need = Ksp + 1, prefix = 0u, pmask = 0u;
#pragma unroll
    for (int pass = 3; pass >= 0; --pass) {
      const int sh = 8 * pass;
      const int pb = pass & 1;
      unsigned* hist = histbuf[pb];
#pragma unroll
      for (int e = 0; e < 16; ++e)
        if ((key[e] & pmask) == prefix) atomicAdd(&hist[(key[e] >> sh) & 255u], 1u);
      __syncthreads();  // A: atomics visible
      unsigned* hz = histbuf[pb ^ 1];  // zero next pass's buffer
      hz[t] = 0u; hz[t + 64] = 0u; hz[t + 128] = 0u; hz[t + 192] = 0u;
      const unsigned c0 = hist[t], c1 = hist[t + 64];
      const unsigned c2 = hist[t + 128], c3 = hist[t + 192];
      unsigned s0 = c0, s1 = c1, s2 = c2, s3 = c3;  // suffix scans (4 chunks)
#pragma unroll
      for (int off = 1; off < 64; off <<= 1) {
        const unsigned y0 = __shfl_down(s0, off), y1 = __shfl_down(s1, off);
        const unsigned y2 = __shfl_down(s2, off), y3 = __shfl_down(s3, off);
        if (t + off < 64) { s0 += y0; s1 += y1; s2 += y2; s3 += y3; }
      }
      const unsigned T1 = __builtin_amdgcn_readfirstlane(s1);
      const unsigned T2 = __builtin_amdgcn_readfirstlane(s2);
      const unsigned T3 = __builtin_amdgcn_readfirstlane(s3);
      const unsigned i0 = s0 + T1 + T2 + T3;  // incl count, bin = t
      const unsigned i1 = s1 + T2 + T3;       // bin = t+64
      const unsigned i2 = s2 + T3;            // bin = t+128
      const unsigned i3 = s3;                 // bin = t+192
      if (i0 >= need && i0 - c0 < need) { sel_prefix = prefix | ((unsigned)t << sh); sel_need = need - (i0 - c0); }
      if (i1 >= need && i1 - c1 < need) { sel_prefix = prefix | ((unsigned)(t + 64) << sh); sel_need = need - (i1 - c1); }
      if (i2 >= need && i2 - c2 < need) { sel_prefix = prefix | ((unsigned)(t + 128) << sh); sel_need = need - (i2 - c2); }
      if (i3 >= need && i3 - c3 < need) { sel_prefix = prefix | ((unsigned)(t + 192) << sh); sel_need = need - (i3 - c3); }
      __syncthreads();  // B: sel_* and zeros visible
      prefix = sel_prefix;
      need = sel_need;
      pmask |= (255u << sh);
    }
    const unsigned Tbits = prefix;

    // ---- ordered compaction (ascending column = group j, then lane, then e) --
    unsigned keep = 0u;
    int mycj[4];
#pragma unroll
    for (int j = 0; j < 4; ++j) {
      int c = 0;
#pragma unroll
      for (int e = 0; e < 4; ++e)
        if (key[j * 4 + e] > Tbits) { keep |= (1u << (j * 4 + e)); ++c; }
      mycj[j] = c;
    }
    int basej[4];
    int total = 0;
#pragma unroll
    for (int j = 0; j < 4; ++j) {
      int x = mycj[j];
#pragma unroll
      for (int off = 1; off < 64; off <<= 1) {  // inclusive prefix scan
        const int y = __shfl_up(x, off);
        if (t >= off) x += y;
      }
      basej[j] = total + x - mycj[j];
      total += __shfl(x, 63);  // group total broadcast
    }
#pragma unroll
    for (int j = 0; j < 4; ++j) {
      int base = basej[j];
#pragma unroll
      for (int e = 0; e < 4; ++e) {
        if (keep & (1u << (j * 4 + e))) {
          sidx[base] = j * 256 + 4 * t + e;
          sval[base] = vals[j * 4 + e];
          ++base;
        }
      }
    }
    if (t == 0) scnt = total;
    if (it == IHT - 1) {
      float4* G4 = (float4*)(gdense + (size_t)b * Md);
#pragma unroll
      for (int j = 0; j < 4; ++j) {
        float4 g;
        g.x = (keep & (1u << (j * 4 + 0))) ? vals[j * 4 + 0] : 0.f;
        g.y = (keep & (1u << (j * 4 + 1))) ? vals[j * 4 + 1] : 0.f;
        g.z = (keep & (1u << (j * 4 + 2))) ? vals[j * 4 + 2] : 0.f;
        g.w = (keep & (1u << (j * 4 + 3))) ? vals[j * 4 + 3] : 0.f;
        G4[j * 64 + t] = g;
      }
    }
    __syncthreads();  // publish sidx/sval/scnt for next iteration
  }

  // ---- epilogue: norms[49] term for final Gamma (same math as R5) ----
  const int cnt = scnt;
  double part = 0.0;
  if (t < cnt) {
    const int id = sidx[t];
    float acc2 = 0.f;
    for (int k = 0; k < cnt; ++k)
      acc2 = fmaf(sval[k], Q[(size_t)sidx[k] * Md + id], acc2);
    part = (double)sval[t] * ((double)acc2 - 2.0 * (double)yws[id]);
  }
  part = wave_reduce_d(part);
  if (t == 0) atomicAdd(&normacc[IHT - 1], part);
}

__global__ void k_wnorms(const double* __restrict__ dacc, float* __restrict__ onorms) {
  const int t = threadIdx.x;
  if (t < IHT) {
    const double yn2 = dacc[0];
    double r2 = yn2 + dacc[1 + t];
    if (r2 < 0.0) r2 = 0.0;
    onorms[t] = (float)(sqrt(r2) / sqrt(yn2));
  }
}

extern "C" void kernel_launch(void* const* d_in, const int* in_sizes, int n_in,
                              void* d_out, int out_size, void* d_ws, size_t ws_size,
                              hipStream_t stream) {
  (void)in_sizes; (void)n_in; (void)out_size; (void)ws_size;  // K hardcoded = 64
  const float* Y = (const float*)d_in[0];  // [1024,512]
  const float* W = (const float*)d_in[1];  // [512,1024]
  float* out = (float*)d_out;
  float* outX = out;                   // [512,1024]
  float* outG = out + Nd * Md;         // [1024,1024]
  float* outN = outG + Bd * Md;        // [50]

  // workspace layout (~11.5 MB)
  char* wsb = (char*)d_ws;
  double* dacc = (double*)wsb;               // 51 doubles
  float* cbuf = (float*)(wsb + 512);         // [0]=c, [1]=eta
  float* Wn = (float*)(wsb + 1024);          // 512*1024
  float* Q = Wn + Nd * Md;                   // 1024*1024
  float* YW = Q + Md * Md;                   // 1024*1024
  float* Smat = YW + Bd * Md;                // 512*512
  float* S2 = Smat + Nd * Nd;                // 512*512
  float* cnorm = S2 + Nd * Nd;               // 1024
  float* X0 = cnorm + Md;                    // 1024
  float* V = X0 + Md;                        // 4*512 power-iter slots

  k_zero<<<1, 64, 0, stream>>>(dacc);
  k_colnorm<<<4, 256, 0, stream>>>(W, cnorm);
  k_normalize<<<2048, 256, 0, stream>>>(W, cnorm, Wn);

  // S = Wn Wn^T (512x512, K=1024); S2 = S*S/64; Q = Wn^T Wn (K=512); YW = Y Wn
  k_gemm_t<64, 32, 2><<<dim3(16, 8), 256, 0, stream>>>(Wn, Md, 0, Wn, Md, 1, Smat, Nd, Md, 1.0f);
  k_gemm_t<64, 32, 2><<<dim3(16, 8), 256, 0, stream>>>(Smat, Nd, 0, Smat, Nd, 0, S2, Nd, Nd, 0.015625f);
  k_gemm_t<64, 64, 4><<<dim3(16, 16), 256, 0, stream>>>(Wn, Md, 1, Wn, Md, 0, Q, Md, Nd, 1.0f);
  k_gemm_t<64, 64, 4><<<dim3(16, 16), 256, 0, stream>>>(Y, Nd, 0, Wn, Md, 0, YW, Md, Nd, 1.0f);
  k_yn2<<<128, 256, 0, stream>>>(Y, dacc);

  // power method in Z-space: z0 = X0 @ Wn^T; 49 steps of S2, 2 steps of S/8
  // (untouched — eta must stay bit-identical)
  k_x0<<<1, 512, 0, stream>>>(X0);
  k_z0<<<128, 256, 0, stream>>>(X0, Wn, V);
  float* pin = V;
  float* pout = V + 512;
  for (int i = 0; i < 49; ++i) {
    k_pmv<<<128, 256, 0, stream>>>(S2, pin, pout, 1.0f);
    float* tp = pin; pin = pout; pout = tp;
  }
  k_pmv<<<128, 256, 0, stream>>>(Smat, pin, V + 1024, 0.125f);        // v99
  k_pmv<<<128, 256, 0, stream>>>(Smat, V + 1024, V + 1536, 0.125f);   // v100
  k_pfinal<<<1, 512, 0, stream>>>(V + 1024, V + 1536, cbuf);

  // IHT: init + 50 iterations + final norm term, ONE wave per row, ONE launch
  k_iht_all<<<1024, 64, 0, stream>>>(Q, YW, cbuf, outG, dacc + 1);
  k_wnorms<<<1, 64, 0, stream>>>(dacc, outN);

  // X = Wn @ Gamma (512x1024, K=1024) reading dense Gamma from d_out
  k_gemm_t<64, 32, 2><<<dim3(32, 8), 256, 0, stream>>>(Wn, Md, 0, outG, Md, 0, outX, Md, Md, 1.0f);
}

// Round 7
// 1066.006 us; speedup vs baseline: 1.1291x; 1.1291x over previous
//
#include <hip/hip_runtime.h>

// DictLearn: W column-normalize -> power method (100 it) -> IHT sparse coding
// (50 it, K=64 hard threshold) -> X = W @ Gamma.
// Outputs in d_out: X [512*1024] fp32, Gamma [1024*1024] fp32, norms [50] fp32.
//
// R7 changes (trajectory bit-identical: fmaf chains, reduce trees, select
// integer math, and eta all unchanged):
//  * k_iht_all: reverted to the R5 structure (256 thr/row, 4 waves — 16
//    waves/CU; R6's 1-wave/row capped the chip at 4 waves/CU and regressed).
//    Only change vs R5: gather unroll 8->16 + __launch_bounds__(256,4).
//  * k_power: the whole power chain (X0 threefry, z0, 49xS2 + 2xS/8 steps,
//    c/eta finalize) in ONE persistent 8-block kernel with device-scope
//    atomic step-barriers — replaces 54 tiny launches (~230us of gaps).
//    Per-row reduction trees verbatim from k_pmv/k_z0/k_pfinal (bit-exact).

#define DEV __device__ __forceinline__

constexpr int Nd = 512;    // signal dim
constexpr int Md = 1024;   // atoms
constexpr int Bd = 1024;   // batch
constexpr int Ksp = 64;    // sparsity K
constexpr int IHT = 50;

DEV float wave_reduce_f(float v) {
#pragma unroll
  for (int off = 32; off > 0; off >>= 1) v += __shfl_down(v, off);
  return v;
}
DEV double wave_reduce_d(double v) {
#pragma unroll
  for (int off = 32; off > 0; off >>= 1) v += __shfl_down(v, off);
  return v;
}
DEV float rfl_f(float v) {
  return __uint_as_float(__builtin_amdgcn_readfirstlane(__float_as_uint(v)));
}

__global__ void k_zero(double* dacc, int* pcnt) {
  int t = threadIdx.x;
  if (t < 51) dacc[t] = 0.0;  // [0]=Yn2, [1..50]=norm accumulators
  if (t < 52) pcnt[t] = 0;    // power-method step barriers
}

__global__ __launch_bounds__(256) void k_colnorm(const float* __restrict__ W,
                                                 float* __restrict__ cnorm) {
  int col = blockIdx.x * 256 + threadIdx.x;  // 1024 cols
  double ss = 0.0;
  for (int i = 0; i < Nd; ++i) {
    float w = W[(size_t)i * Md + col];
    ss = fma((double)w, (double)w, ss);
  }
  cnorm[col] = (float)sqrt(ss);
}

__global__ __launch_bounds__(256) void k_normalize(const float* __restrict__ W,
                                                   const float* __restrict__ cnorm,
                                                   float* __restrict__ Wn) {
  int idx = blockIdx.x * 256 + threadIdx.x;  // 512*1024
  Wn[idx] = W[idx] / cnorm[idx & (Md - 1)];
}

__global__ __launch_bounds__(256) void k_yn2(const float* __restrict__ Y,
                                             double* __restrict__ dacc) {
  double s = 0.0;
  for (int i = blockIdx.x * 256 + threadIdx.x; i < Bd * Nd; i += gridDim.x * 256) {
    float y = Y[i];
    s = fma((double)y, (double)y, s);
  }
  s = wave_reduce_d(s);
  __shared__ double red[4];
  int lane = threadIdx.x & 63, wid = threadIdx.x >> 6;
  if (lane == 0) red[wid] = s;
  __syncthreads();
  if (threadIdx.x == 0) atomicAdd(&dacc[0], red[0] + red[1] + red[2] + red[3]);
}

// C[m,n] = scale * sum_k A(m,k)*B(k,n); ta/tb: operand stored transposed.
// BMxBN tile, 256 threads, 4xTN per thread, BK=32, register double-buffered
// staging. Per-element accumulation k0-ascending, kk-ascending (bit-stable).
template <int BM, int BN, int TN>
__global__ __launch_bounds__(256) void k_gemm_t(const float* __restrict__ A, int lda, int ta,
                                                const float* __restrict__ B, int ldb, int tb,
                                                float* __restrict__ C, int ldc, int Kd,
                                                float scale) {
  constexpr int AE = 32 * BM / 256;
  constexpr int BE = 32 * BN / 256;
  __shared__ __align__(16) float As[32][BM + 4];  // [kk][m]
  __shared__ __align__(16) float Bs[32][BN + 4];  // [kk][n]
  const int tid = threadIdx.x;
  const int tx = tid % (BN / TN), ty = tid / (BN / TN);
  const int m0 = blockIdx.y * BM, n0 = blockIdx.x * BN;
  float ra[AE], rb[BE];
  float acc[4][TN];
#pragma unroll
  for (int i = 0; i < 4; ++i)
#pragma unroll
    for (int j = 0; j < TN; ++j) acc[i][j] = 0.f;

  auto loadA = [&](int k0) {
    if (!ta) {
      const int c = tid & 31, r0 = tid >> 5;
#pragma unroll
      for (int i = 0; i < AE; ++i)
        ra[i] = A[(size_t)(m0 + r0 + i * 8) * lda + (k0 + c)];
    } else {
      const int r = tid % BM, c0 = tid / BM;
#pragma unroll
      for (int i = 0; i < AE; ++i)
        ra[i] = A[(size_t)(k0 + c0 + i * (256 / BM)) * lda + (m0 + r)];
    }
  };
  auto storeA = [&]() {
    if (!ta) {
      const int c = tid & 31, r0 = tid >> 5;
#pragma unroll
      for (int i = 0; i < AE; ++i) As[c][r0 + i * 8] = ra[i];
    } else {
      const int r = tid % BM, c0 = tid / BM;
#pragma unroll
      for (int i = 0; i < AE; ++i) As[c0 + i * (256 / BM)][r] = ra[i];
    }
  };
  auto loadB = [&](int k0) {
    if (!tb) {
      const int c = tid % BN, r0 = tid / BN;
#pragma unroll
      for (int i = 0; i < BE; ++i)
        rb[i] = B[(size_t)(k0 + r0 + i * (256 / BN)) * ldb + (n0 + c)];
    } else {
      const int r = tid & 31, c0 = tid >> 5;
#pragma unroll
      for (int i = 0; i < BE; ++i)
        rb[i] = B[(size_t)(n0 + c0 + i * 8) * ldb + (k0 + r)];
    }
  };
  auto storeB = [&]() {
    if (!tb) {
      const int c = tid % BN, r0 = tid / BN;
#pragma unroll
      for (int i = 0; i < BE; ++i) Bs[r0 + i * (256 / BN)][c] = rb[i];
    } else {
      const int r = tid & 31, c0 = tid >> 5;
#pragma unroll
      for (int i = 0; i < BE; ++i) Bs[r][c0 + i * 8] = rb[i];
    }
  };

  loadA(0);
  loadB(0);
  storeA();
  storeB();
  __syncthreads();
  for (int k0 = 0; k0 < Kd; k0 += 32) {
    const bool more = (k0 + 32) < Kd;
    if (more) { loadA(k0 + 32); loadB(k0 + 32); }  // prefetch into regs
#pragma unroll
    for (int kk = 0; kk < 32; ++kk) {
      const float4 a4 = *(const float4*)&As[kk][ty * 4];
      const float aa[4] = {a4.x, a4.y, a4.z, a4.w};
      float bb[TN];
      if constexpr (TN == 4) {
        const float4 b4 = *(const float4*)&Bs[kk][tx * 4];
        bb[0] = b4.x; bb[1] = b4.y; bb[2] = b4.z; bb[3] = b4.w;
      } else {
        const float2 b2 = *(const float2*)&Bs[kk][tx * 2];
        bb[0] = b2.x; bb[1] = b2.y;
      }
#pragma unroll
      for (int i = 0; i < 4; ++i)
#pragma unroll
        for (int j = 0; j < TN; ++j) acc[i][j] = fmaf(aa[i], bb[j], acc[i][j]);
    }
    if (more) {
      __syncthreads();
      storeA();
      storeB();
      __syncthreads();
    }
  }
#pragma unroll
  for (int i = 0; i < 4; ++i) {
    if constexpr (TN == 4) {
      float4 o;
      o.x = acc[i][0] * scale; o.y = acc[i][1] * scale;
      o.z = acc[i][2] * scale; o.w = acc[i][3] * scale;
      *(float4*)&C[(size_t)(m0 + ty * 4 + i) * ldc + n0 + tx * 4] = o;
    } else {
      float2 o;
      o.x = acc[i][0] * scale; o.y = acc[i][1] * scale;
      *(float2*)&C[(size_t)(m0 + ty * 4 + i) * ldc + n0 + tx * 2] = o;
    }
  }
}

// XLA ErfInvF32 (Giles) — matches jax/XLA erf_inv on f32.
DEV float erfinv_xla(float x) {
  float w = -log1pf(-x * x);
  float p;
  if (w < 5.0f) {
    w = w - 2.5f;
    p = 2.81022636e-08f;
    p = fmaf(p, w, 3.43273939e-07f);
    p = fmaf(p, w, -3.5233877e-06f);
    p = fmaf(p, w, -4.39150654e-06f);
    p = fmaf(p, w, 0.00021858087f);
    p = fmaf(p, w, -0.00125372503f);
    p = fmaf(p, w, -0.00417768164f);
    p = fmaf(p, w, 0.246640727f);
    p = fmaf(p, w, 1.50140941f);
  } else {
    w = sqrtf(w) - 3.0f;
    p = -0.000200214257f;
    p = fmaf(p, w, 0.000100950558f);
    p = fmaf(p, w, 0.00134934322f);
    p = fmaf(p, w, -0.00367342844f);
    p = fmaf(p, w, 0.00573950773f);
    p = fmaf(p, w, -0.0076224613f);
    p = fmaf(p, w, 0.00943887047f);
    p = fmaf(p, w, 1.00167406f);
    p = fmaf(p, w, 2.83297682f);
  }
  return p * x;
}

#define TF_ROUND(r)                                  \
  {                                                  \
    x0 += x1;                                        \
    x1 = (x1 << (r)) | (x1 >> (32 - (r)));           \
    x1 ^= x0;                                        \
  }

// Entire power chain in one persistent kernel: 8 blocks x 512 threads,
// device-scope atomic barrier per step (8 blocks are always co-resident on a
// 256-CU chip; counters re-zeroed by k_zero every call). Per-row math and
// reduction trees are verbatim k_x0/k_z0/k_pmv/k_pfinal (bit-identical —
// row->wave remapping does not change any per-row fmaf/shuffle chain).
__global__ __launch_bounds__(512) void k_power(const float* __restrict__ Wn,
                                               const float* __restrict__ S2,
                                               const float* __restrict__ Smat,
                                               float* __restrict__ V,
                                               float* __restrict__ cbuf,
                                               int* __restrict__ pcnt) {
  __shared__ float xbuf[Md];
  __shared__ double r99[8], r100[8];
  const int t = threadIdx.x, lane = t & 63, wv = t >> 6;
  const int bk = blockIdx.x;  // 0..7
  const int nblk = (int)gridDim.x;

  // ---- X0 = jax.random.normal(key(42),(1,1024)) bits (redundant per block) --
  {
    unsigned i = (unsigned)t;  // 0..511; counter pair (i, i+512)
    unsigned x0 = i, x1 = i + 512u;
    const unsigned ks0 = 0u, ks1 = 42u, ks2 = 0x1BD11BDAu ^ 42u;
    x0 += ks0; x1 += ks1;
    TF_ROUND(13) TF_ROUND(15) TF_ROUND(26) TF_ROUND(6)  x0 += ks1; x1 += ks2 + 1u;
    TF_ROUND(17) TF_ROUND(29) TF_ROUND(16) TF_ROUND(24) x0 += ks2; x1 += ks0 + 2u;
    TF_ROUND(13) TF_ROUND(15) TF_ROUND(26) TF_ROUND(6)  x0 += ks0; x1 += ks1 + 3u;
    TF_ROUND(17) TF_ROUND(29) TF_ROUND(16) TF_ROUND(24) x0 += ks1; x1 += ks2 + 4u;
    TF_ROUND(13) TF_ROUND(15) TF_ROUND(26) TF_ROUND(6)  x0 += ks2; x1 += ks0 + 5u;
    const float lo = -0.99999994f;
    const float sqrt2 = 1.41421356237f;
    {
      float f = __uint_as_float((x0 >> 9) | 0x3f800000u) - 1.0f;
      float u = fmaxf(lo, f * 2.0f + lo);
      xbuf[i] = sqrt2 * erfinv_xla(u);
    }
    {
      float f = __uint_as_float((x1 >> 9) | 0x3f800000u) - 1.0f;
      float u = fmaxf(lo, f * 2.0f + lo);
      xbuf[i + 512] = sqrt2 * erfinv_xla(u);
    }
  }
  __syncthreads();

  float* s0 = V;
  float* s1 = V + 512;
  float* v99 = V + 1024;
  float* v100 = V + 1536;
  const int w = bk * 8 + wv;  // global wave id 0..63

  // ---- z0 = X0 @ Wn^T (rows 512; per-row tree verbatim k_z0) ----
  for (int i = 0; i < 8; ++i) {
    const int row = w + 64 * i;
    const float4* wr = (const float4*)(Wn + (size_t)row * Md);
    const float4* x4 = (const float4*)xbuf;
    float s = 0.f;
#pragma unroll
    for (int e = 0; e < 4; ++e) {
      const float4 w4 = wr[lane + e * 64];
      const float4 xx = x4[lane + e * 64];
      s = fmaf(w4.x, xx.x, s); s = fmaf(w4.y, xx.y, s);
      s = fmaf(w4.z, xx.z, s); s = fmaf(w4.w, xx.w, s);
    }
    s = wave_reduce_f(s);
    if (lane == 0) s0[row] = s;
  }
  __syncthreads();
  if (t == 0) {
    __hip_atomic_fetch_add(&pcnt[0], 1, __ATOMIC_RELEASE, __HIP_MEMORY_SCOPE_AGENT);
    while (__hip_atomic_load(&pcnt[0], __ATOMIC_ACQUIRE, __HIP_MEMORY_SCOPE_AGENT) < nblk) {}
  }
  __syncthreads();

  // ---- 49 steps of S2 (scale 1), then 2 steps of Smat (scale 1/8) ----
  const float* pin = s0;
  for (int step = 0; step < 51; ++step) {
    const float* M;
    float scale;
    float* dst;
    if (step < 49)      { M = S2;   scale = 1.0f;   dst = (step & 1) ? s0 : s1; }
    else if (step == 49){ M = Smat; scale = 0.125f; dst = v99; }
    else                { M = Smat; scale = 0.125f; dst = v100; }
    for (int i = 0; i < 8; ++i) {
      const int row = w + 64 * i;
      const float4* mr = (const float4*)(M + (size_t)row * Nd);
      const float4* v4 = (const float4*)pin;
      float s = 0.f;
#pragma unroll
      for (int e = 0; e < 2; ++e) {
        const float4 m4 = mr[lane + e * 64];
        const float4 xx = v4[lane + e * 64];
        s = fmaf(m4.x, xx.x, s); s = fmaf(m4.y, xx.y, s);
        s = fmaf(m4.z, xx.z, s); s = fmaf(m4.w, xx.w, s);
      }
      s = wave_reduce_f(s);
      if (lane == 0) dst[row] = s * scale;
    }
    __syncthreads();
    if (t == 0) {
      __hip_atomic_fetch_add(&pcnt[1 + step], 1, __ATOMIC_RELEASE, __HIP_MEMORY_SCOPE_AGENT);
      while (__hip_atomic_load(&pcnt[1 + step], __ATOMIC_ACQUIRE, __HIP_MEMORY_SCOPE_AGENT) < nblk) {}
    }
    __syncthreads();
    pin = dst;
  }

  // ---- finalize c, eta (verbatim k_pfinal tree; block 0 only) ----
  if (bk == 0) {
    double a = (double)v99[t]; a *= a;
    double b2 = (double)v100[t]; b2 *= b2;
    a = wave_reduce_d(a);
    b2 = wave_reduce_d(b2);
    if (lane == 0) { r99[wv] = a; r100[wv] = b2; }
    __syncthreads();
    if (t == 0) {
      double n99 = 0.0, n100 = 0.0;
      for (int i = 0; i < 8; ++i) { n99 += r99[i]; n100 += r100[i]; }
      float c = (float)(8.0 * sqrt(n100 / n99));  // last pre-norm ||X2||
      cbuf[0] = c;
      cbuf[1] = 1.0f / c;  // eta
    }
  }
}

// ALL IHT iterations fused: one workgroup (256 thr, 4 waves) per batch row —
// the R5 structure (best measured). Math bit-identical to R5; only the gather
// unroll deepened to 16 (fma application order unchanged, k-ascending).
__global__ __launch_bounds__(256, 4) void k_iht_all(
    const float* __restrict__ Q, const float* __restrict__ YW,
    const float* __restrict__ cbuf, float* __restrict__ gdense,
    double* __restrict__ normacc) {
  __shared__ float u[Md];
  __shared__ float yws[Md];
  __shared__ float sval[Ksp];
  __shared__ int sidx[Ksp];
  __shared__ unsigned histbuf[2][4][256];  // [parity][wave][bin]
  __shared__ unsigned wred[4];
  __shared__ unsigned sel_need, sel_prefix;
  __shared__ double dred[4];
  __shared__ int scnt;

  const int t = threadIdx.x;
  const int b = blockIdx.x;
  const int lane = t & 63, wv = t >> 6;
  const float eta = cbuf[1];
  const float4 yw = ((const float4*)(YW + (size_t)b * Md))[t];  // row in regs
  ((float4*)yws)[t] = yw;                                        // + LDS copy
#pragma unroll
  for (int e = 0; e < 8; ++e) ((unsigned*)histbuf)[t + e * 256] = 0u;
  const float* Qt = Q + t * 4;  // per-thread column base; row base is scalar

  for (int it = -1; it < IHT; ++it) {
    if (it >= 0) {
      const int cnt = scnt;
      float4 p = make_float4(0.f, 0.f, 0.f, 0.f);
      int k = 0;
      for (; k + 16 <= cnt; k += 16) {  // 16 saddr loads in flight
        int ids[16];
        float gs[16];
        float4 qq[16];
#pragma unroll
        for (int j = 0; j < 16; ++j) {
          ids[j] = __builtin_amdgcn_readfirstlane(sidx[k + j]);
          gs[j] = rfl_f(sval[k + j]);
        }
#pragma unroll
        for (int j = 0; j < 16; ++j) qq[j] = *(const float4*)(Qt + (size_t)ids[j] * Md);
#pragma unroll
        for (int j = 0; j < 16; ++j) p.x = fmaf(gs[j], qq[j].x, p.x);
#pragma unroll
        for (int j = 0; j < 16; ++j) p.y = fmaf(gs[j], qq[j].y, p.y);
#pragma unroll
        for (int j = 0; j < 16; ++j) p.z = fmaf(gs[j], qq[j].z, p.z);
#pragma unroll
        for (int j = 0; j < 16; ++j) p.w = fmaf(gs[j], qq[j].w, p.w);
      }
      for (; k < cnt; ++k) {
        const int id = __builtin_amdgcn_readfirstlane(sidx[k]);
        const float g = rfl_f(sval[k]);
        const float4 q = *(const float4*)(Qt + (size_t)id * Md);
        p.x = fmaf(g, q.x, p.x); p.y = fmaf(g, q.y, p.y);
        p.z = fmaf(g, q.z, p.z); p.w = fmaf(g, q.w, p.w);
      }
      ((float4*)u)[t] = p;  // u holds P for the norm dot
      __syncthreads();      // B1: P visible
      if (it >= 1) {
        double part = 0.0;
        if (t < cnt) {
          const int id = sidx[t];
          part = (double)sval[t] * ((double)u[id] - 2.0 * (double)yws[id]);
        }
        part = wave_reduce_d(part);
        if (lane == 0) dred[wv] = part;
      }
      __syncthreads();      // B2: dred visible; all u reads done
      if (it >= 1 && t == 0)
        atomicAdd(&normacc[it - 1], dred[0] + dred[1] + dred[2] + dred[3]);
      float4 uu;
      uu.x = -(eta * (p.x - yw.x)); uu.y = -(eta * (p.y - yw.y));
      uu.z = -(eta * (p.z - yw.z)); uu.w = -(eta * (p.w - yw.w));
      ((float4*)u)[t] = uu;
      __syncthreads();      // B3: uu visible
      if (t < cnt) u[sidx[t]] += sval[t];  // distinct indices, no race
      __syncthreads();      // B4
    } else {
      float4 uu;
      uu.x = eta * yw.x; uu.y = eta * yw.y; uu.z = eta * yw.z; uu.w = eta * yw.w;
      ((float4*)u)[t] = uu;
      __syncthreads();      // also publishes yws + histbuf zeros
    }

    // keys/vals in registers for all passes + compaction
    float vals[4];
    unsigned key[4];
    {
      const float4 mv = ((const float4*)u)[t];
      vals[0] = mv.x; vals[1] = mv.y; vals[2] = mv.z; vals[3] = mv.w;
#pragma unroll
      for (int e = 0; e < 4; ++e) key[e] = __float_as_uint(vals[e]) & 0x7fffffffu;
    }

    // ---- radix select: exact bit pattern of the (K+1)-th largest |u| ----
    unsigned need = Ksp + 1, prefix = 0u, pmask = 0u;
#pragma unroll
    for (int pass = 3; pass >= 0; --pass) {
      const int sh = 8 * pass;
      const int pb = pass & 1;
      unsigned(*hist)[256] = histbuf[pb];
#pragma unroll
      for (int e = 0; e < 4; ++e)
        if ((key[e] & pmask) == prefix) atomicAdd(&hist[wv][(key[e] >> sh) & 255u], 1u);
      __syncthreads();  // A: atomics visible
      unsigned* hz = histbuf[pb ^ 1][wv];  // zero next pass's buffer
      hz[lane] = 0u; hz[lane + 64] = 0u; hz[lane + 128] = 0u; hz[lane + 192] = 0u;
      if (wv == 0) {
        const unsigned c0 = hist[0][lane] + hist[1][lane] + hist[2][lane] + hist[3][lane];
        const unsigned c1 = hist[0][lane + 64] + hist[1][lane + 64] + hist[2][lane + 64] + hist[3][lane + 64];
        const unsigned c2 = hist[0][lane + 128] + hist[1][lane + 128] + hist[2][lane + 128] + hist[3][lane + 128];
        const unsigned c3 = hist[0][lane + 192] + hist[1][lane + 192] + hist[2][lane + 192] + hist[3][lane + 192];
        unsigned s0 = c0, s1 = c1, s2 = c2, s3 = c3;  // suffix scans (4 chunks)
#pragma unroll
        for (int off = 1; off < 64; off <<= 1) {
          const unsigned y0 = __shfl_down(s0, off), y1 = __shfl_down(s1, off);
          const unsigned y2 = __shfl_down(s2, off), y3 = __shfl_down(s3, off);
          if (lane + off < 64) { s0 += y0; s1 += y1; s2 += y2; s3 += y3; }
        }
        const unsigned T1 = __builtin_amdgcn_readfirstlane(s1);
        const unsigned T2 = __builtin_amdgcn_readfirstlane(s2);
        const unsigned T3 = __builtin_amdgcn_readfirstlane(s3);
        const unsigned i0 = s0 + T1 + T2 + T3;  // incl count, bin = lane
        const unsigned i1 = s1 + T2 + T3;       // bin = lane+64
        const unsigned i2 = s2 + T3;            // bin = lane+128
        const unsigned i3 = s3;                 // bin = lane+192
        if (i0 >= need && i0 - c0 < need) { sel_prefix = prefix | ((unsigned)lane << sh); sel_need = need - (i0 - c0); }
        if (i1 >= need && i1 - c1 < need) { sel_prefix = prefix | ((unsigned)(lane + 64) << sh); sel_need = need - (i1 - c1); }
        if (i2 >= need && i2 - c2 < need) { sel_prefix = prefix | ((unsigned)(lane + 128) << sh); sel_need = need - (i2 - c2); }
        if (i3 >= need && i3 - c3 < need) { sel_prefix = prefix | ((unsigned)(lane + 192) << sh); sel_need = need - (i3 - c3); }
      }
      __syncthreads();  // B: sel_* and zeros visible
      prefix = sel_prefix;
      need = sel_need;
      pmask |= (255u << sh);
    }
    const unsigned Tbits = prefix;

    // ---- ordered compaction (deterministic, ascending column order) ----
    unsigned keep = 0u;
    unsigned myc = 0u;
#pragma unroll
    for (int e = 0; e < 4; ++e)
      if (key[e] > Tbits) { keep |= (1u << e); ++myc; }
    unsigned x = myc;
#pragma unroll
    for (int off = 1; off < 64; off <<= 1) {  // wave inclusive prefix scan
      const unsigned y = __shfl_up(x, off);
      if (lane >= off) x += y;
    }
    if (lane == 63) wred[wv] = x;  // wave total
    __syncthreads();  // C1: wred visible
    unsigned addlo = 0u;
    for (int w2 = 0; w2 < wv; ++w2) addlo += wred[w2];
    int base = (int)(x + addlo) - (int)myc;  // exclusive prefix in thread order
#pragma unroll
    for (int e = 0; e < 4; ++e) {
      if (keep & (1u << e)) {
        sidx[base] = t * 4 + e;
        sval[base] = vals[e];
        ++base;
      }
    }
    if (t == 0) scnt = (int)(wred[0] + wred[1] + wred[2] + wred[3]);
    if (it == IHT - 1) {
      float4 g;
      g.x = (keep & 1u) ? vals[0] : 0.f;
      g.y = (keep & 2u) ? vals[1] : 0.f;
      g.z = (keep & 4u) ? vals[2] : 0.f;
      g.w = (keep & 8u) ? vals[3] : 0.f;
      ((float4*)(gdense + (size_t)b * Md))[t] = g;
    }
    __syncthreads();  // C2: publish sidx/sval/scnt for next iteration
  }

  // ---- epilogue: norms[49] term for final Gamma ----
  const int cnt = scnt;
  if (wv == 0) {
    double part = 0.0;
    if (lane < cnt) {
      const int id = sidx[lane];
      float acc2 = 0.f;
      for (int k = 0; k < cnt; ++k)
        acc2 = fmaf(sval[k], Q[(size_t)sidx[k] * Md + id], acc2);
      part = (double)sval[lane] * ((double)acc2 - 2.0 * (double)yws[id]);
    }
    part = wave_reduce_d(part);
    if (lane == 0) atomicAdd(&normacc[IHT - 1], part);
  }
}

__global__ void k_wnorms(const double* __restrict__ dacc, float* __restrict__ onorms) {
  const int t = threadIdx.x;
  if (t < IHT) {
    const double yn2 = dacc[0];
    double r2 = yn2 + dacc[1 + t];
    if (r2 < 0.0) r2 = 0.0;
    onorms[t] = (float)(sqrt(r2) / sqrt(yn2));
  }
}

extern "C" void kernel_launch(void* const* d_in, const int* in_sizes, int n_in,
                              void* d_out, int out_size, void* d_ws, size_t ws_size,
                              hipStream_t stream) {
  (void)in_sizes; (void)n_in; (void)out_size; (void)ws_size;  // K hardcoded = 64
  const float* Y = (const float*)d_in[0];  // [1024,512]
  const float* W = (const float*)d_in[1];  // [512,1024]
  float* out = (float*)d_out;
  float* outX = out;                   // [512,1024]
  float* outG = out + Nd * Md;         // [1024,1024]
  float* outN = outG + Bd * Md;        // [50]

  // workspace layout (~11.5 MB)
  char* wsb = (char*)d_ws;
  double* dacc = (double*)wsb;               // 51 doubles
  float* cbuf = (float*)(wsb + 512);         // [0]=c, [1]=eta
  float* Wn = (float*)(wsb + 1024);          // 512*1024
  float* Q = Wn + Nd * Md;                   // 1024*1024
  float* YW = Q + Md * Md;                   // 1024*1024
  float* Smat = YW + Bd * Md;                // 512*512
  float* S2 = Smat + Nd * Nd;                // 512*512
  float* cnorm = S2 + Nd * Nd;               // 1024
  float* V = cnorm + Md;                     // 4*512 power-iter slots
  int* pcnt = (int*)(V + 2048);              // 52 step counters

  k_zero<<<1, 64, 0, stream>>>(dacc, pcnt);
  k_colnorm<<<4, 256, 0, stream>>>(W, cnorm);
  k_normalize<<<2048, 256, 0, stream>>>(W, cnorm, Wn);

  // S = Wn Wn^T (512x512, K=1024); S2 = S*S/64; Q = Wn^T Wn (K=512); YW = Y Wn
  k_gemm_t<64, 32, 2><<<dim3(16, 8), 256, 0, stream>>>(Wn, Md, 0, Wn, Md, 1, Smat, Nd, Md, 1.0f);
  k_gemm_t<64, 32, 2><<<dim3(16, 8), 256, 0, stream>>>(Smat, Nd, 0, Smat, Nd, 0, S2, Nd, Nd, 0.015625f);
  k_gemm_t<64, 64, 4><<<dim3(16, 16), 256, 0, stream>>>(Wn, Md, 1, Wn, Md, 0, Q, Md, Nd, 1.0f);
  k_gemm_t<64, 64, 4><<<dim3(16, 16), 256, 0, stream>>>(Y, Nd, 0, Wn, Md, 0, YW, Md, Nd, 1.0f);
  k_yn2<<<128, 256, 0, stream>>>(Y, dacc);

  // power method: ONE persistent launch (X0, z0, 49xS2 + 2xS/8, c/eta)
  k_power<<<8, 512, 0, stream>>>(Wn, S2, Smat, V, cbuf, pcnt);

  // IHT: init + 50 iterations + final norm term, all in ONE launch
  k_iht_all<<<1024, 256, 0, stream>>>(Q, YW, cbuf, outG, dacc + 1);
  k_wnorms<<<1, 64, 0, stream>>>(dacc, outN);

  // X = Wn @ Gamma (512x1024, K=1024) reading dense Gamma from d_out
  k_gemm_t<64, 32, 2><<<dim3(32, 8), 256, 0, stream>>>(Wn, Md, 0, outG, Md, 0, outX, Md, Md, 1.0f);
}

// Round 8
// 1010.420 us; speedup vs baseline: 1.1912x; 1.0550x over previous
//
#include <hip/hip_runtime.h>

// DictLearn: W column-normalize -> power method (100 it) -> IHT sparse coding
// (50 it, K=64 hard threshold) -> X = W @ Gamma.
// Outputs in d_out: X [512*1024] fp32, Gamma [1024*1024] fp32, norms [50] fp32.
//
// R8 changes vs R7 (trajectory bit-identical: fmaf chains, reduce trees,
// select integer math, and eta all unchanged):
//  * k_power barrier: distributed per-block flag lines (release STORE, no
//    RMW line-bouncing) + one-vector-load poll (lane i polls flag i) with
//    s_sleep backoff. R7's single-counter fetch_add barrier bounced one
//    cache line across XCDs (~5.5us/step -> k_power ~300us, worse than the
//    graph-replayed 51-launch chain it replaced).
//  * k_power scaled 8 -> 16 blocks (more matvec BW/step; poll cost flat).
//  * k_iht_all verbatim R7 (653us, best measured).

#define DEV __device__ __forceinline__

constexpr int Nd = 512;    // signal dim
constexpr int Md = 1024;   // atoms
constexpr int Bd = 1024;   // batch
constexpr int Ksp = 64;    // sparsity K
constexpr int IHT = 50;
constexpr int NBLK = 16;   // k_power blocks (flag barrier participants)

DEV float wave_reduce_f(float v) {
#pragma unroll
  for (int off = 32; off > 0; off >>= 1) v += __shfl_down(v, off);
  return v;
}
DEV double wave_reduce_d(double v) {
#pragma unroll
  for (int off = 32; off > 0; off >>= 1) v += __shfl_down(v, off);
  return v;
}
DEV float rfl_f(float v) {
  return __uint_as_float(__builtin_amdgcn_readfirstlane(__float_as_uint(v)));
}

__global__ __launch_bounds__(512) void k_zero(double* dacc, int* pcnt) {
  int t = threadIdx.x;
  if (t < 51) dacc[t] = 0.0;   // [0]=Yn2, [1..50]=norm accumulators
  pcnt[t] = 0;                 // 512 ints: NBLK flag lines (stride 32)
}

__global__ __launch_bounds__(256) void k_colnorm(const float* __restrict__ W,
                                                 float* __restrict__ cnorm) {
  int col = blockIdx.x * 256 + threadIdx.x;  // 1024 cols
  double ss = 0.0;
  for (int i = 0; i < Nd; ++i) {
    float w = W[(size_t)i * Md + col];
    ss = fma((double)w, (double)w, ss);
  }
  cnorm[col] = (float)sqrt(ss);
}

__global__ __launch_bounds__(256) void k_normalize(const float* __restrict__ W,
                                                   const float* __restrict__ cnorm,
                                                   float* __restrict__ Wn) {
  int idx = blockIdx.x * 256 + threadIdx.x;  // 512*1024
  Wn[idx] = W[idx] / cnorm[idx & (Md - 1)];
}

__global__ __launch_bounds__(256) void k_yn2(const float* __restrict__ Y,
                                             double* __restrict__ dacc) {
  double s = 0.0;
  for (int i = blockIdx.x * 256 + threadIdx.x; i < Bd * Nd; i += gridDim.x * 256) {
    float y = Y[i];
    s = fma((double)y, (double)y, s);
  }
  s = wave_reduce_d(s);
  __shared__ double red[4];
  int lane = threadIdx.x & 63, wid = threadIdx.x >> 6;
  if (lane == 0) red[wid] = s;
  __syncthreads();
  if (threadIdx.x == 0) atomicAdd(&dacc[0], red[0] + red[1] + red[2] + red[3]);
}

// C[m,n] = scale * sum_k A(m,k)*B(k,n); ta/tb: operand stored transposed.
// BMxBN tile, 256 threads, 4xTN per thread, BK=32, register double-buffered
// staging. Per-element accumulation k0-ascending, kk-ascending (bit-stable).
template <int BM, int BN, int TN>
__global__ __launch_bounds__(256) void k_gemm_t(const float* __restrict__ A, int lda, int ta,
                                                const float* __restrict__ B, int ldb, int tb,
                                                float* __restrict__ C, int ldc, int Kd,
                                                float scale) {
  constexpr int AE = 32 * BM / 256;
  constexpr int BE = 32 * BN / 256;
  __shared__ __align__(16) float As[32][BM + 4];  // [kk][m]
  __shared__ __align__(16) float Bs[32][BN + 4];  // [kk][n]
  const int tid = threadIdx.x;
  const int tx = tid % (BN / TN), ty = tid / (BN / TN);
  const int m0 = blockIdx.y * BM, n0 = blockIdx.x * BN;
  float ra[AE], rb[BE];
  float acc[4][TN];
#pragma unroll
  for (int i = 0; i < 4; ++i)
#pragma unroll
    for (int j = 0; j < TN; ++j) acc[i][j] = 0.f;

  auto loadA = [&](int k0) {
    if (!ta) {
      const int c = tid & 31, r0 = tid >> 5;
#pragma unroll
      for (int i = 0; i < AE; ++i)
        ra[i] = A[(size_t)(m0 + r0 + i * 8) * lda + (k0 + c)];
    } else {
      const int r = tid % BM, c0 = tid / BM;
#pragma unroll
      for (int i = 0; i < AE; ++i)
        ra[i] = A[(size_t)(k0 + c0 + i * (256 / BM)) * lda + (m0 + r)];
    }
  };
  auto storeA = [&]() {
    if (!ta) {
      const int c = tid & 31, r0 = tid >> 5;
#pragma unroll
      for (int i = 0; i < AE; ++i) As[c][r0 + i * 8] = ra[i];
    } else {
      const int r = tid % BM, c0 = tid / BM;
#pragma unroll
      for (int i = 0; i < AE; ++i) As[c0 + i * (256 / BM)][r] = ra[i];
    }
  };
  auto loadB = [&](int k0) {
    if (!tb) {
      const int c = tid % BN, r0 = tid / BN;
#pragma unroll
      for (int i = 0; i < BE; ++i)
        rb[i] = B[(size_t)(k0 + r0 + i * (256 / BN)) * ldb + (n0 + c)];
    } else {
      const int r = tid & 31, c0 = tid >> 5;
#pragma unroll
      for (int i = 0; i < BE; ++i)
        rb[i] = B[(size_t)(n0 + c0 + i * 8) * ldb + (k0 + r)];
    }
  };
  auto storeB = [&]() {
    if (!tb) {
      const int c = tid % BN, r0 = tid / BN;
#pragma unroll
      for (int i = 0; i < BE; ++i) Bs[r0 + i * (256 / BN)][c] = rb[i];
    } else {
      const int r = tid & 31, c0 = tid >> 5;
#pragma unroll
      for (int i = 0; i < BE; ++i) Bs[r][c0 + i * 8] = rb[i];
    }
  };

  loadA(0);
  loadB(0);
  storeA();
  storeB();
  __syncthreads();
  for (int k0 = 0; k0 < Kd; k0 += 32) {
    const bool more = (k0 + 32) < Kd;
    if (more) { loadA(k0 + 32); loadB(k0 + 32); }  // prefetch into regs
#pragma unroll
    for (int kk = 0; kk < 32; ++kk) {
      const float4 a4 = *(const float4*)&As[kk][ty * 4];
      const float aa[4] = {a4.x, a4.y, a4.z, a4.w};
      float bb[TN];
      if constexpr (TN == 4) {
        const float4 b4 = *(const float4*)&Bs[kk][tx * 4];
        bb[0] = b4.x; bb[1] = b4.y; bb[2] = b4.z; bb[3] = b4.w;
      } else {
        const float2 b2 = *(const float2*)&Bs[kk][tx * 2];
        bb[0] = b2.x; bb[1] = b2.y;
      }
#pragma unroll
      for (int i = 0; i < 4; ++i)
#pragma unroll
        for (int j = 0; j < TN; ++j) acc[i][j] = fmaf(aa[i], bb[j], acc[i][j]);
    }
    if (more) {
      __syncthreads();
      storeA();
      storeB();
      __syncthreads();
    }
  }
#pragma unroll
  for (int i = 0; i < 4; ++i) {
    if constexpr (TN == 4) {
      float4 o;
      o.x = acc[i][0] * scale; o.y = acc[i][1] * scale;
      o.z = acc[i][2] * scale; o.w = acc[i][3] * scale;
      *(float4*)&C[(size_t)(m0 + ty * 4 + i) * ldc + n0 + tx * 4] = o;
    } else {
      float2 o;
      o.x = acc[i][0] * scale; o.y = acc[i][1] * scale;
      *(float2*)&C[(size_t)(m0 + ty * 4 + i) * ldc + n0 + tx * 2] = o;
    }
  }
}

// XLA ErfInvF32 (Giles) — matches jax/XLA erf_inv on f32.
DEV float erfinv_xla(float x) {
  float w = -log1pf(-x * x);
  float p;
  if (w < 5.0f) {
    w = w - 2.5f;
    p = 2.81022636e-08f;
    p = fmaf(p, w, 3.43273939e-07f);
    p = fmaf(p, w, -3.5233877e-06f);
    p = fmaf(p, w, -4.39150654e-06f);
    p = fmaf(p, w, 0.00021858087f);
    p = fmaf(p, w, -0.00125372503f);
    p = fmaf(p, w, -0.00417768164f);
    p = fmaf(p, w, 0.246640727f);
    p = fmaf(p, w, 1.50140941f);
  } else {
    w = sqrtf(w) - 3.0f;
    p = -0.000200214257f;
    p = fmaf(p, w, 0.000100950558f);
    p = fmaf(p, w, 0.00134934322f);
    p = fmaf(p, w, -0.00367342844f);
    p = fmaf(p, w, 0.00573950773f);
    p = fmaf(p, w, -0.0076224613f);
    p = fmaf(p, w, 0.00943887047f);
    p = fmaf(p, w, 1.00167406f);
    p = fmaf(p, w, 2.83297682f);
  }
  return p * x;
}

#define TF_ROUND(r)                                  \
  {                                                  \
    x0 += x1;                                        \
    x1 = (x1 << (r)) | (x1 >> (32 - (r)));           \
    x1 ^= x0;                                        \
  }

// Entire power chain in one persistent kernel: NBLK blocks x 512 threads.
// Distributed flag barrier: block b release-STOREs its own flag line
// (pcnt[b*32], 128B apart — no RMW bouncing); wave 0 polls all flags with a
// single vector ACQUIRE load (lane i -> flag i) + __all, s_sleep backoff.
// Per-row math and reduction trees verbatim k_x0/k_z0/k_pmv/k_pfinal
// (bit-identical — row->wave remapping doesn't change any per-row chain).
__global__ __launch_bounds__(512) void k_power(const float* __restrict__ Wn,
                                               const float* __restrict__ S2,
                                               const float* __restrict__ Smat,
                                               float* __restrict__ V,
                                               float* __restrict__ cbuf,
                                               int* __restrict__ pcnt) {
  __shared__ float xbuf[Md];
  __shared__ double r99[8], r100[8];
  const int t = threadIdx.x, lane = t & 63, wv = t >> 6;
  const int bk = blockIdx.x;  // 0..NBLK-1

  auto flag_barrier = [&](int val) {
    __syncthreads();  // all waves done with this step's writes
    if (t == 0)
      __hip_atomic_store(&pcnt[bk * 32], val, __ATOMIC_RELEASE,
                         __HIP_MEMORY_SCOPE_AGENT);
    if (wv == 0) {
      while (true) {
        int f = (lane < NBLK)
                    ? __hip_atomic_load(&pcnt[lane * 32], __ATOMIC_ACQUIRE,
                                        __HIP_MEMORY_SCOPE_AGENT)
                    : val;
        if (__all(f >= val)) break;
        __builtin_amdgcn_s_sleep(1);
      }
    }
    __syncthreads();
  };

  // ---- X0 = jax.random.normal(key(42),(1,1024)) bits (redundant per block) --
  {
    unsigned i = (unsigned)t;  // 0..511; counter pair (i, i+512)
    unsigned x0 = i, x1 = i + 512u;
    const unsigned ks0 = 0u, ks1 = 42u, ks2 = 0x1BD11BDAu ^ 42u;
    x0 += ks0; x1 += ks1;
    TF_ROUND(13) TF_ROUND(15) TF_ROUND(26) TF_ROUND(6)  x0 += ks1; x1 += ks2 + 1u;
    TF_ROUND(17) TF_ROUND(29) TF_ROUND(16) TF_ROUND(24) x0 += ks2; x1 += ks0 + 2u;
    TF_ROUND(13) TF_ROUND(15) TF_ROUND(26) TF_ROUND(6)  x0 += ks0; x1 += ks1 + 3u;
    TF_ROUND(17) TF_ROUND(29) TF_ROUND(16) TF_ROUND(24) x0 += ks1; x1 += ks2 + 4u;
    TF_ROUND(13) TF_ROUND(15) TF_ROUND(26) TF_ROUND(6)  x0 += ks2; x1 += ks0 + 5u;
    const float lo = -0.99999994f;
    const float sqrt2 = 1.41421356237f;
    {
      float f = __uint_as_float((x0 >> 9) | 0x3f800000u) - 1.0f;
      float u = fmaxf(lo, f * 2.0f + lo);
      xbuf[i] = sqrt2 * erfinv_xla(u);
    }
    {
      float f = __uint_as_float((x1 >> 9) | 0x3f800000u) - 1.0f;
      float u = fmaxf(lo, f * 2.0f + lo);
      xbuf[i + 512] = sqrt2 * erfinv_xla(u);
    }
  }
  __syncthreads();

  float* s0 = V;
  float* s1 = V + 512;
  float* v99 = V + 1024;
  float* v100 = V + 1536;
  const int w = bk * 8 + wv;               // global wave id 0..NBLK*8-1
  constexpr int NW = NBLK * 8;             // 128 waves
  constexpr int RPW = 512 / NW;            // rows per wave = 4

  // ---- z0 = X0 @ Wn^T (rows 512; per-row tree verbatim k_z0) ----
  for (int i = 0; i < RPW; ++i) {
    const int row = w + NW * i;
    const float4* wr = (const float4*)(Wn + (size_t)row * Md);
    const float4* x4 = (const float4*)xbuf;
    float s = 0.f;
#pragma unroll
    for (int e = 0; e < 4; ++e) {
      const float4 w4 = wr[lane + e * 64];
      const float4 xx = x4[lane + e * 64];
      s = fmaf(w4.x, xx.x, s); s = fmaf(w4.y, xx.y, s);
      s = fmaf(w4.z, xx.z, s); s = fmaf(w4.w, xx.w, s);
    }
    s = wave_reduce_f(s);
    if (lane == 0) s0[row] = s;
  }
  flag_barrier(1);

  // ---- 49 steps of S2 (scale 1), then 2 steps of Smat (scale 1/8) ----
  const float* pin = s0;
  for (int step = 0; step < 51; ++step) {
    const float* M;
    float scale;
    float* dst;
    if (step < 49)      { M = S2;   scale = 1.0f;   dst = (step & 1) ? s0 : s1; }
    else if (step == 49){ M = Smat; scale = 0.125f; dst = v99; }
    else                { M = Smat; scale = 0.125f; dst = v100; }
    for (int i = 0; i < RPW; ++i) {
      const int row = w + NW * i;
      const float4* mr = (const float4*)(M + (size_t)row * Nd);
      const float4* v4 = (const float4*)pin;
      float s = 0.f;
#pragma unroll
      for (int e = 0; e < 2; ++e) {
        const float4 m4 = mr[lane + e * 64];
        const float4 xx = v4[lane + e * 64];
        s = fmaf(m4.x, xx.x, s); s = fmaf(m4.y, xx.y, s);
        s = fmaf(m4.z, xx.z, s); s = fmaf(m4.w, xx.w, s);
      }
      s = wave_reduce_f(s);
      if (lane == 0) dst[row] = s * scale;
    }
    flag_barrier(step + 2);
    pin = dst;
  }

  // ---- finalize c, eta (verbatim k_pfinal tree; block 0 only) ----
  if (bk == 0) {
    double a = (double)v99[t]; a *= a;
    double b2 = (double)v100[t]; b2 *= b2;
    a = wave_reduce_d(a);
    b2 = wave_reduce_d(b2);
    if (lane == 0) { r99[wv] = a; r100[wv] = b2; }
    __syncthreads();
    if (t == 0) {
      double n99 = 0.0, n100 = 0.0;
      for (int i = 0; i < 8; ++i) { n99 += r99[i]; n100 += r100[i]; }
      float c = (float)(8.0 * sqrt(n100 / n99));  // last pre-norm ||X2||
      cbuf[0] = c;
      cbuf[1] = 1.0f / c;  // eta
    }
  }
}

// ALL IHT iterations fused: one workgroup (256 thr, 4 waves) per batch row —
// verbatim R7 (best measured: 653us).
__global__ __launch_bounds__(256, 4) void k_iht_all(
    const float* __restrict__ Q, const float* __restrict__ YW,
    const float* __restrict__ cbuf, float* __restrict__ gdense,
    double* __restrict__ normacc) {
  __shared__ float u[Md];
  __shared__ float yws[Md];
  __shared__ float sval[Ksp];
  __shared__ int sidx[Ksp];
  __shared__ unsigned histbuf[2][4][256];  // [parity][wave][bin]
  __shared__ unsigned wred[4];
  __shared__ unsigned sel_need, sel_prefix;
  __shared__ double dred[4];
  __shared__ int scnt;

  const int t = threadIdx.x;
  const int b = blockIdx.x;
  const int lane = t & 63, wv = t >> 6;
  const float eta = cbuf[1];
  const float4 yw = ((const float4*)(YW + (size_t)b * Md))[t];  // row in regs
  ((float4*)yws)[t] = yw;                                        // + LDS copy
#pragma unroll
  for (int e = 0; e < 8; ++e) ((unsigned*)histbuf)[t + e * 256] = 0u;
  const float* Qt = Q + t * 4;  // per-thread column base; row base is scalar

  for (int it = -1; it < IHT; ++it) {
    if (it >= 0) {
      const int cnt = scnt;
      float4 p = make_float4(0.f, 0.f, 0.f, 0.f);
      int k = 0;
      for (; k + 16 <= cnt; k += 16) {  // 16 saddr loads in flight
        int ids[16];
        float gs[16];
        float4 qq[16];
#pragma unroll
        for (int j = 0; j < 16; ++j) {
          ids[j] = __builtin_amdgcn_readfirstlane(sidx[k + j]);
          gs[j] = rfl_f(sval[k + j]);
        }
#pragma unroll
        for (int j = 0; j < 16; ++j) qq[j] = *(const float4*)(Qt + (size_t)ids[j] * Md);
#pragma unroll
        for (int j = 0; j < 16; ++j) p.x = fmaf(gs[j], qq[j].x, p.x);
#pragma unroll
        for (int j = 0; j < 16; ++j) p.y = fmaf(gs[j], qq[j].y, p.y);
#pragma unroll
        for (int j = 0; j < 16; ++j) p.z = fmaf(gs[j], qq[j].z, p.z);
#pragma unroll
        for (int j = 0; j < 16; ++j) p.w = fmaf(gs[j], qq[j].w, p.w);
      }
      for (; k < cnt; ++k) {
        const int id = __builtin_amdgcn_readfirstlane(sidx[k]);
        const float g = rfl_f(sval[k]);
        const float4 q = *(const float4*)(Qt + (size_t)id * Md);
        p.x = fmaf(g, q.x, p.x); p.y = fmaf(g, q.y, p.y);
        p.z = fmaf(g, q.z, p.z); p.w = fmaf(g, q.w, p.w);
      }
      ((float4*)u)[t] = p;  // u holds P for the norm dot
      __syncthreads();      // B1: P visible
      if (it >= 1) {
        double part = 0.0;
        if (t < cnt) {
          const int id = sidx[t];
          part = (double)sval[t] * ((double)u[id] - 2.0 * (double)yws[id]);
        }
        part = wave_reduce_d(part);
        if (lane == 0) dred[wv] = part;
      }
      __syncthreads();      // B2: dred visible; all u reads done
      if (it >= 1 && t == 0)
        atomicAdd(&normacc[it - 1], dred[0] + dred[1] + dred[2] + dred[3]);
      float4 uu;
      uu.x = -(eta * (p.x - yw.x)); uu.y = -(eta * (p.y - yw.y));
      uu.z = -(eta * (p.z - yw.z)); uu.w = -(eta * (p.w - yw.w));
      ((float4*)u)[t] = uu;
      __syncthreads();      // B3: uu visible
      if (t < cnt) u[sidx[t]] += sval[t];  // distinct indices, no race
      __syncthreads();      // B4
    } else {
      float4 uu;
      uu.x = eta * yw.x; uu.y = eta * yw.y; uu.z = eta * yw.z; uu.w = eta * yw.w;
      ((float4*)u)[t] = uu;
      __syncthreads();      // also publishes yws + histbuf zeros
    }

    // keys/vals in registers for all passes + compaction
    float vals[4];
    unsigned key[4];
    {
      const float4 mv = ((const float4*)u)[t];
      vals[0] = mv.x; vals[1] = mv.y; vals[2] = mv.z; vals[3] = mv.w;
#pragma unroll
      for (int e = 0; e < 4; ++e) key[e] = __float_as_uint(vals[e]) & 0x7fffffffu;
    }

    // ---- radix select: exact bit pattern of the (K+1)-th largest |u| ----
    unsigned need = Ksp + 1, prefix = 0u, pmask = 0u;
#pragma unroll
    for (int pass = 3; pass >= 0; --pass) {
      const int sh = 8 * pass;
      const int pb = pass & 1;
      unsigned(*hist)[256] = histbuf[pb];
#pragma unroll
      for (int e = 0; e < 4; ++e)
        if ((key[e] & pmask) == prefix) atomicAdd(&hist[wv][(key[e] >> sh) & 255u], 1u);
      __syncthreads();  // A: atomics visible
      unsigned* hz = histbuf[pb ^ 1][wv];  // zero next pass's buffer
      hz[lane] = 0u; hz[lane + 64] = 0u; hz[lane + 128] = 0u; hz[lane + 192] = 0u;
      if (wv == 0) {
        const unsigned c0 = hist[0][lane] + hist[1][lane] + hist[2][lane] + hist[3][lane];
        const unsigned c1 = hist[0][lane + 64] + hist[1][lane + 64] + hist[2][lane + 64] + hist[3][lane + 64];
        const unsigned c2 = hist[0][lane + 128] + hist[1][lane + 128] + hist[2][lane + 128] + hist[3][lane + 128];
        const unsigned c3 = hist[0][lane + 192] + hist[1][lane + 192] + hist[2][lane + 192] + hist[3][lane + 192];
        unsigned s0 = c0, s1 = c1, s2 = c2, s3 = c3;  // suffix scans (4 chunks)
#pragma unroll
        for (int off = 1; off < 64; off <<= 1) {
          const unsigned y0 = __shfl_down(s0, off), y1 = __shfl_down(s1, off);
          const unsigned y2 = __shfl_down(s2, off), y3 = __shfl_down(s3, off);
          if (lane + off < 64) { s0 += y0; s1 += y1; s2 += y2; s3 += y3; }
        }
        const unsigned T1 = __builtin_amdgcn_readfirstlane(s1);
        const unsigned T2 = __builtin_amdgcn_readfirstlane(s2);
        const unsigned T3 = __builtin_amdgcn_readfirstlane(s3);
        const unsigned i0 = s0 + T1 + T2 + T3;  // incl count, bin = lane
        const unsigned i1 = s1 + T2 + T3;       // bin = lane+64
        const unsigned i2 = s2 + T3;            // bin = lane+128
        const unsigned i3 = s3;                 // bin = lane+192
        if (i0 >= need && i0 - c0 < need) { sel_prefix = prefix | ((unsigned)lane << sh); sel_need = need - (i0 - c0); }
        if (i1 >= need && i1 - c1 < need) { sel_prefix = prefix | ((unsigned)(lane + 64) << sh); sel_need = need - (i1 - c1); }
        if (i2 >= need && i2 - c2 < need) { sel_prefix = prefix | ((unsigned)(lane + 128) << sh); sel_need = need - (i2 - c2); }
        if (i3 >= need && i3 - c3 < need) { sel_prefix = prefix | ((unsigned)(lane + 192) << sh); sel_need = need - (i3 - c3); }
      }
      __syncthreads();  // B: sel_* and zeros visible
      prefix = sel_prefix;
      need = sel_need;
      pmask |= (255u << sh);
    }
    const unsigned Tbits = prefix;

    // ---- ordered compaction (deterministic, ascending column order) ----
    unsigned keep = 0u;
    unsigned myc = 0u;
#pragma unroll
    for (int e = 0; e < 4; ++e)
      if (key[e] > Tbits) { keep |= (1u << e); ++myc; }
    unsigned x = myc;
#pragma unroll
    for (int off = 1; off < 64; off <<= 1) {  // wave inclusive prefix scan
      const unsigned y = __shfl_up(x, off);
      if (lane >= off) x += y;
    }
    if (lane == 63) wred[wv] = x;  // wave total
    __syncthreads();  // C1: wred visible
    unsigned addlo = 0u;
    for (int w2 = 0; w2 < wv; ++w2) addlo += wred[w2];
    int base = (int)(x + addlo) - (int)myc;  // exclusive prefix in thread order
#pragma unroll
    for (int e = 0; e < 4; ++e) {
      if (keep & (1u << e)) {
        sidx[base] = t * 4 + e;
        sval[base] = vals[e];
        ++base;
      }
    }
    if (t == 0) scnt = (int)(wred[0] + wred[1] + wred[2] + wred[3]);
    if (it == IHT - 1) {
      float4 g;
      g.x = (keep & 1u) ? vals[0] : 0.f;
      g.y = (keep & 2u) ? vals[1] : 0.f;
      g.z = (keep & 4u) ? vals[2] : 0.f;
      g.w = (keep & 8u) ? vals[3] : 0.f;
      ((float4*)(gdense + (size_t)b * Md))[t] = g;
    }
    __syncthreads();  // C2: publish sidx/sval/scnt for next iteration
  }

  // ---- epilogue: norms[49] term for final Gamma ----
  const int cnt = scnt;
  if (wv == 0) {
    double part = 0.0;
    if (lane < cnt) {
      const int id = sidx[lane];
      float acc2 = 0.f;
      for (int k = 0; k < cnt; ++k)
        acc2 = fmaf(sval[k], Q[(size_t)sidx[k] * Md + id], acc2);
      part = (double)sval[lane] * ((double)acc2 - 2.0 * (double)yws[id]);
    }
    part = wave_reduce_d(part);
    if (lane == 0) atomicAdd(&normacc[IHT - 1], part);
  }
}

__global__ void k_wnorms(const double* __restrict__ dacc, float* __restrict__ onorms) {
  const int t = threadIdx.x;
  if (t < IHT) {
    const double yn2 = dacc[0];
    double r2 = yn2 + dacc[1 + t];
    if (r2 < 0.0) r2 = 0.0;
    onorms[t] = (float)(sqrt(r2) / sqrt(yn2));
  }
}

extern "C" void kernel_launch(void* const* d_in, const int* in_sizes, int n_in,
                              void* d_out, int out_size, void* d_ws, size_t ws_size,
                              hipStream_t stream) {
  (void)in_sizes; (void)n_in; (void)out_size; (void)ws_size;  // K hardcoded = 64
  const float* Y = (const float*)d_in[0];  // [1024,512]
  const float* W = (const float*)d_in[1];  // [512,1024]
  float* out = (float*)d_out;
  float* outX = out;                   // [512,1024]
  float* outG = out + Nd * Md;         // [1024,1024]
  float* outN = outG + Bd * Md;        // [50]

  // workspace layout (~11.5 MB)
  char* wsb = (char*)d_ws;
  double* dacc = (double*)wsb;               // 51 doubles
  float* cbuf = (float*)(wsb + 512);         // [0]=c, [1]=eta
  float* Wn = (float*)(wsb + 1024);          // 512*1024
  float* Q = Wn + Nd * Md;                   // 1024*1024
  float* YW = Q + Md * Md;                   // 1024*1024
  float* Smat = YW + Bd * Md;                // 512*512
  float* S2 = Smat + Nd * Nd;                // 512*512
  float* cnorm = S2 + Nd * Nd;               // 1024
  float* V = cnorm + Md;                     // 4*512 power-iter slots
  int* pcnt = (int*)(V + 2048);              // NBLK flag lines (512 ints)

  k_zero<<<1, 512, 0, stream>>>(dacc, pcnt);
  k_colnorm<<<4, 256, 0, stream>>>(W, cnorm);
  k_normalize<<<2048, 256, 0, stream>>>(W, cnorm, Wn);

  // S = Wn Wn^T (512x512, K=1024); S2 = S*S/64; Q = Wn^T Wn (K=512); YW = Y Wn
  k_gemm_t<64, 32, 2><<<dim3(16, 8), 256, 0, stream>>>(Wn, Md, 0, Wn, Md, 1, Smat, Nd, Md, 1.0f);
  k_gemm_t<64, 32, 2><<<dim3(16, 8), 256, 0, stream>>>(Smat, Nd, 0, Smat, Nd, 0, S2, Nd, Nd, 0.015625f);
  k_gemm_t<64, 64, 4><<<dim3(16, 16), 256, 0, stream>>>(Wn, Md, 1, Wn, Md, 0, Q, Md, Nd, 1.0f);
  k_gemm_t<64, 64, 4><<<dim3(16, 16), 256, 0, stream>>>(Y, Nd, 0, Wn, Md, 0, YW, Md, Nd, 1.0f);
  k_yn2<<<128, 256, 0, stream>>>(Y, dacc);

  // power method: ONE persistent launch (X0, z0, 49xS2 + 2xS/8, c/eta)
  k_power<<<NBLK, 512, 0, stream>>>(Wn, S2, Smat, V, cbuf, pcnt);

  // IHT: init + 50 iterations + final norm term, all in ONE launch
  k_iht_all<<<1024, 256, 0, stream>>>(Q, YW, cbuf, outG, dacc + 1);
  k_wnorms<<<1, 64, 0, stream>>>(dacc, outN);

  // X = Wn @ Gamma (512x1024, K=1024) reading dense Gamma from d_out
  k_gemm_t<64, 32, 2><<<dim3(32, 8), 256, 0, stream>>>(Wn, Md, 0, outG, Md, 0, outX, Md, Md, 1.0f);
}